// Round 1
// baseline (1238.535 us; speedup 1.0000x reference)
//
#include <hip/hip_runtime.h>
#include <math.h>

#define V 30000
#define H 512
#define NB 16
#define NS 256
#define NJ 10
#define NT 8
#define NOPS 4
#define NR 160          // NJ*NB rows
#define EV 30720        // padded E row stride (15*2048)
#define NEGV -1e9f

typedef __attribute__((ext_vector_type(8))) short short8;
typedef __attribute__((ext_vector_type(4))) float f32x4;

__device__ inline float bf2f(unsigned short s) {
    union { unsigned int u; float f; } c; c.u = ((unsigned int)s) << 16;
    return c.f;
}
__device__ inline unsigned short f2bf(float f) {
    union { float f; unsigned int u; } c; c.f = f;
    unsigned int u = c.u;
    u += 0x7fffu + ((u >> 16) & 1u);   // RNE
    return (unsigned short)(u >> 16);
}

// ---------------- setup: convert emb_W to bf16 ----------------
__global__ void k_setup_emb(const float* __restrict__ emb, unsigned short* __restrict__ emb_bf, int n8) {
    int gid = blockIdx.x * 256 + threadIdx.x;
    if (gid >= n8) return;
    const float4* src = (const float4*)emb + (size_t)gid * 2;
    float4 a = src[0], b = src[1];
    short8 o;
    o[0] = (short)f2bf(a.x); o[1] = (short)f2bf(a.y); o[2] = (short)f2bf(a.z); o[3] = (short)f2bf(a.w);
    o[4] = (short)f2bf(b.x); o[5] = (short)f2bf(b.y); o[6] = (short)f2bf(b.z); o[7] = (short)f2bf(b.w);
    *(short8*)(emb_bf + (size_t)gid * 8) = o;
}

// ---------------- setup: W splits + initial w/h state ----------------
__global__ void k_setup_small(const float* __restrict__ Wih, const float* __restrict__ Whh,
    unsigned short* wih_hi, unsigned short* wih_lo, unsigned short* whh_hi, unsigned short* whh_lo,
    const float* __restrict__ slot, const float* __restrict__ ench,
    float* w_g, unsigned short* w_hi, unsigned short* w_lo,
    float* h_g, unsigned short* h_hi, unsigned short* h_lo)
{
    int gid = blockIdx.x * 256 + threadIdx.x;
    if (gid < 786432) {
        float v1 = Wih[gid];
        unsigned short hi = f2bf(v1);
        wih_hi[gid] = hi; wih_lo[gid] = f2bf(v1 - bf2f(hi));
        float v2 = Whh[gid];
        hi = f2bf(v2);
        whh_hi[gid] = hi; whh_lo[gid] = f2bf(v2 - bf2f(hi));
    } else {
        int i = gid - 786432;
        if (i < NR * H) {
            int jb = i >> 9, d = i & 511;
            int j = jb >> 4, b = jb & 15;
            float wv = slot[j * H + d];
            w_g[i] = wv;
            unsigned short hi = f2bf(wv);
            w_hi[i] = hi; w_lo[i] = f2bf(wv - bf2f(hi));
            float hv = ench[b * H + d];
            h_g[i] = hv;
            hi = f2bf(hv);
            h_hi[i] = hi; h_lo[i] = f2bf(hv - bf2f(hi));
        }
    }
}

// ---------------- GRU GEMMs: gi = w @ W_ih^T, gh = h @ W_hh^T (split-bf16, fp32-accurate) ----
#define GRU_APAD 520
__global__ __launch_bounds__(256) void k_gru_gemm(
    const unsigned short* __restrict__ w_hi, const unsigned short* __restrict__ w_lo,
    const unsigned short* __restrict__ h_hi, const unsigned short* __restrict__ h_lo,
    const unsigned short* __restrict__ wih_hi, const unsigned short* __restrict__ wih_lo,
    const unsigned short* __restrict__ whh_hi, const unsigned short* __restrict__ whh_lo,
    float* __restrict__ gi, float* __restrict__ gh)
{
    __shared__ unsigned short Ah[16 * GRU_APAD];
    __shared__ unsigned short Al[16 * GRU_APAD];
    int nch = blockIdx.x, mt = blockIdx.y, z = blockIdx.z;
    const unsigned short* Asrc_hi = z ? h_hi : w_hi;
    const unsigned short* Asrc_lo = z ? h_lo : w_lo;
    const unsigned short* Bhi = z ? whh_hi : wih_hi;
    const unsigned short* Blo = z ? whh_lo : wih_lo;
    float* outp = z ? gh : gi;
    int t = threadIdx.x;
    for (int i = t; i < 2048; i += 256) {
        int matl = i >> 10;
        int row = (i >> 6) & 15;
        int seg = i & 63;
        const unsigned short* src = (matl ? Asrc_lo : Asrc_hi) + (mt * 16 + row) * 512 + seg * 8;
        unsigned short* dst = (matl ? Al : Ah) + row * GRU_APAD + seg * 8;
        *(short8*)dst = *(const short8*)src;
    }
    __syncthreads();
    int wv = t >> 6, lane = t & 63;
    int col15 = lane & 15, quad = lane >> 4;
    f32x4 acc0 = {0.f, 0.f, 0.f, 0.f}, acc1 = {0.f, 0.f, 0.f, 0.f};
    int c0 = nch * 128 + wv * 32 + col15;
    int c1 = c0 + 16;
    const unsigned short* bhp0 = Bhi + c0 * 512 + quad * 8;
    const unsigned short* bhp1 = Bhi + c1 * 512 + quad * 8;
    const unsigned short* blp0 = Blo + c0 * 512 + quad * 8;
    const unsigned short* blp1 = Blo + c1 * 512 + quad * 8;
    const unsigned short* ahp = Ah + col15 * GRU_APAD + quad * 8;
    const unsigned short* alp = Al + col15 * GRU_APAD + quad * 8;
#pragma unroll
    for (int ks = 0; ks < 16; ks++) {
        int ko = ks * 32;
        short8 bh0 = *(const short8*)(bhp0 + ko);
        short8 bh1 = *(const short8*)(bhp1 + ko);
        short8 bl0 = *(const short8*)(blp0 + ko);
        short8 bl1 = *(const short8*)(blp1 + ko);
        short8 ah = *(const short8*)(ahp + ko);
        short8 al = *(const short8*)(alp + ko);
        acc0 = __builtin_amdgcn_mfma_f32_16x16x32_bf16(ah, bh0, acc0, 0, 0, 0);
        acc1 = __builtin_amdgcn_mfma_f32_16x16x32_bf16(ah, bh1, acc1, 0, 0, 0);
        acc0 = __builtin_amdgcn_mfma_f32_16x16x32_bf16(ah, bl0, acc0, 0, 0, 0);
        acc1 = __builtin_amdgcn_mfma_f32_16x16x32_bf16(ah, bl1, acc1, 0, 0, 0);
        acc0 = __builtin_amdgcn_mfma_f32_16x16x32_bf16(al, bh0, acc0, 0, 0, 0);
        acc1 = __builtin_amdgcn_mfma_f32_16x16x32_bf16(al, bh1, acc1, 0, 0, 0);
    }
#pragma unroll
    for (int r = 0; r < 4; r++) {
        int row = mt * 16 + quad * 4 + r;
        outp[row * 1536 + c0] = acc0[r];
        outp[row * 1536 + c1] = acc1[r];
    }
}

// --------- fused: GRU pointwise + attention scores + softmax + context + p_gen -------------
__global__ __launch_bounds__(256) void k_attention(
    const float* __restrict__ gi, const float* __restrict__ gh,
    const float* __restrict__ b_ih, const float* __restrict__ b_hh,
    float* __restrict__ h_g, unsigned short* __restrict__ h_hi, unsigned short* __restrict__ h_lo,
    const float* __restrict__ enc, const int* __restrict__ x,
    const float* __restrict__ w_g, const float* __restrict__ wgenW, const float* __restrict__ wgenb,
    float* __restrict__ attn_g, float* __restrict__ pgen_g,
    float* __restrict__ ctx0, int store_ctx)
{
    __shared__ float h_lds[512];
    __shared__ float sc[256];
    __shared__ float red[256];
    int jb = blockIdx.x;
    int b = jb & 15;
    int t = threadIdx.x;
    // GRU pointwise (PyTorch gate order r,z,n)
    for (int d = t; d < 512; d += 256) {
        int base = jb * 1536;
        float ir = gi[base + d]        + b_ih[d];
        float iz = gi[base + 512 + d]  + b_ih[512 + d];
        float in = gi[base + 1024 + d] + b_ih[1024 + d];
        float hr = gh[base + d]        + b_hh[d];
        float hz = gh[base + 512 + d]  + b_hh[512 + d];
        float hn = gh[base + 1024 + d] + b_hh[1024 + d];
        float hold = h_g[jb * 512 + d];
        float r = 1.f / (1.f + expf(-(ir + hr)));
        float z = 1.f / (1.f + expf(-(iz + hz)));
        float n = tanhf(in + r * hn);
        float hnew = (1.f - z) * n + z * hold;
        h_lds[d] = hnew;
        h_g[jb * 512 + d] = hnew;
        unsigned short hi = f2bf(hnew);
        h_hi[jb * 512 + d] = hi;
        h_lo[jb * 512 + d] = f2bf(hnew - bf2f(hi));
    }
    __syncthreads();
    int wid = t >> 6, lane = t & 63;
    float hreg[8];
#pragma unroll
    for (int i = 0; i < 8; i++) hreg[i] = h_lds[lane * 8 + i];
    const float* encb = enc + (size_t)b * NS * H;
    for (int s = wid; s < NS; s += 4) {
        const float4* er = (const float4*)(encb + s * 512 + lane * 8);
        float4 e0 = er[0], e1 = er[1];
        float p = e0.x * hreg[0] + e0.y * hreg[1] + e0.z * hreg[2] + e0.w * hreg[3]
                + e1.x * hreg[4] + e1.y * hreg[5] + e1.z * hreg[6] + e1.w * hreg[7];
#pragma unroll
        for (int off = 32; off > 0; off >>= 1) p += __shfl_down(p, off);
        if (lane == 0) sc[s] = (x[b * NS + s] == 0) ? NEGV : p;
    }
    __syncthreads();
    // softmax over s
    red[t] = sc[t];
    __syncthreads();
    for (int sft = 128; sft > 0; sft >>= 1) { if (t < sft) red[t] = fmaxf(red[t], red[t + sft]); __syncthreads(); }
    float m = red[0];
    __syncthreads();
    float e = expf(sc[t] - m);
    red[t] = e;
    __syncthreads();
    for (int sft = 128; sft > 0; sft >>= 1) { if (t < sft) red[t] += red[t + sft]; __syncthreads(); }
    float inv = 1.f / red[0];
    float p_s = e * inv;
    sc[t] = p_s;
    attn_g[jb * NS + t] = p_s;
    __syncthreads();
    // context (dims 2t, 2t+1)
    float c0 = 0.f, c1 = 0.f;
    const float2* enc2 = (const float2*)encb + t;
    for (int s = 0; s < NS; s++) {
        float ps = sc[s];
        float2 ev = enc2[s * 256];
        c0 += ps * ev.x; c1 += ps * ev.y;
    }
    if (store_ctx) ((float2*)ctx0)[jb * 256 + t] = make_float2(c0, c1);
    int d0 = 2 * t, d1 = 2 * t + 1;
    float pg = wgenW[d0] * w_g[jb * 512 + d0] + wgenW[d1] * w_g[jb * 512 + d1]
             + wgenW[512 + d0] * h_lds[d0] + wgenW[512 + d1] * h_lds[d1]
             + wgenW[1024 + d0] * c0 + wgenW[1024 + d1] * c1;
    red[t] = pg;
    __syncthreads();
    for (int sft = 128; sft > 0; sft >>= 1) { if (t < sft) red[t] += red[t + sft]; __syncthreads(); }
    if (t == 0) pgen_g[jb] = 1.f / (1.f + expf(-(red[0] + wgenb[0])));
}

// ---------------- gate head (step 0 context only) ----------------
__global__ __launch_bounds__(256) void k_gates(const float* __restrict__ ctx0,
    const float* __restrict__ aW, const float* __restrict__ ab, float* __restrict__ out)
{
    __shared__ float red[256];
    int jb = blockIdx.x; int j = jb >> 4, b = jb & 15; int t = threadIdx.x;
    float part[4] = {0.f, 0.f, 0.f, 0.f};
    for (int d = t; d < 512; d += 256) {
        float c = ctx0[jb * 512 + d];
#pragma unroll
        for (int o = 0; o < 4; o++) part[o] += c * aW[o * 512 + d];
    }
    for (int o = 0; o < 4; o++) {
        red[t] = part[o];
        __syncthreads();
        for (int sft = 128; sft > 0; sft >>= 1) { if (t < sft) red[t] += red[t + sft]; __syncthreads(); }
        if (t == 0) out[(b * NJ + j) * NOPS + o] = red[0] + ab[o];
        __syncthreads();
    }
}

// ---------------- vocab GEMM: E = exp(h_bf16 @ embW_bf16^T), bf16 out ----------------
#define VPAD 136
__global__ __launch_bounds__(256) void k_vgemm(
    const unsigned short* __restrict__ h_hi, const unsigned short* __restrict__ emb_bf,
    unsigned short* __restrict__ E)
{
    __shared__ unsigned short A[160 * VPAD];
    int blk = blockIdx.x;
    int t = threadIdx.x;
    int wv = t >> 6, lane = t & 63, col15 = lane & 15, quad = lane >> 4;
    int v = blk * 128 + wv * 32 + col15;
    f32x4 acc[10][2];
#pragma unroll
    for (int m = 0; m < 10; m++) {
        acc[m][0] = (f32x4){0.f, 0.f, 0.f, 0.f};
        acc[m][1] = (f32x4){0.f, 0.f, 0.f, 0.f};
    }
    int v0c = min(v, V - 1);
    int v1c = min(v + 16, V - 1);
    for (int kc = 0; kc < 4; kc++) {
        __syncthreads();
        for (int i = t; i < 2560; i += 256) {
            int row = i >> 4, seg = i & 15;
            *(short8*)(A + row * VPAD + seg * 8) = *(const short8*)(h_hi + row * 512 + kc * 128 + seg * 8);
        }
        __syncthreads();
#pragma unroll
        for (int ks = 0; ks < 4; ks++) {
            int kl = ks * 32 + quad * 8;
            int kg = kc * 128 + kl;
            short8 b0 = *(const short8*)(emb_bf + (size_t)v0c * 512 + kg);
            short8 b1 = *(const short8*)(emb_bf + (size_t)v1c * 512 + kg);
#pragma unroll
            for (int m = 0; m < 10; m++) {
                short8 a = *(const short8*)(A + (m * 16 + col15) * VPAD + kl);
                acc[m][0] = __builtin_amdgcn_mfma_f32_16x16x32_bf16(a, b0, acc[m][0], 0, 0, 0);
                acc[m][1] = __builtin_amdgcn_mfma_f32_16x16x32_bf16(a, b1, acc[m][1], 0, 0, 0);
            }
        }
    }
#pragma unroll
    for (int m = 0; m < 10; m++) {
#pragma unroll
        for (int tile = 0; tile < 2; tile++) {
            int vv = v + tile * 16;
#pragma unroll
            for (int r = 0; r < 4; r++) {
                int row = m * 16 + quad * 4 + r;
                float val = acc[m][tile][r];
                unsigned short evs = (vv < V) ? f2bf(expf(val)) : (unsigned short)0;
                E[(size_t)row * EV + vv] = evs;
            }
        }
    }
}

// ------- finalize: rowsum + dense p write + pointer scatter + argmax + w_next gather -------
__global__ __launch_bounds__(256) void k_finalize(
    const unsigned short* __restrict__ E, const float* __restrict__ pgen_g,
    const float* __restrict__ attn_g, const int* __restrict__ x,
    const float* __restrict__ emb, float* __restrict__ out,
    float* __restrict__ w_g, unsigned short* __restrict__ w_hi, unsigned short* __restrict__ w_lo,
    int tstep)
{
    __shared__ float red[256];
    __shared__ float bvs[256];
    __shared__ int bis[256];
    int jb = blockIdx.x, t = threadIdx.x;
    int j = jb >> 4, b = jb & 15;
    const unsigned short* Er = E + (size_t)jb * EV;
    float lsum = 0.f;
    for (int i = 0; i < 15; i++) {
        short8 ev = *(const short8*)(Er + (i * 256 + t) * 8);
#pragma unroll
        for (int k = 0; k < 8; k++) lsum += bf2f((unsigned short)ev[k]);
    }
    red[t] = lsum;
    __syncthreads();
    for (int sft = 128; sft > 0; sft >>= 1) { if (t < sft) red[t] += red[t + sft]; __syncthreads(); }
    float inv = 1.f / red[0];
    float pgen = pgen_g[jb];
    size_t outbase = (size_t)640 + ((size_t)(b * NJ + j) * NT + tstep) * V;
    float* op = out + outbase;
    float best = -1.f; int besti = 0x7fffffff;
    for (int i = 0; i < 15; i++) {
        int vb = (i * 256 + t) * 8;
        short8 ev = *(const short8*)(Er + vb);
#pragma unroll
        for (int k = 0; k < 8; k++) {
            int vv = vb + k;
            if (vv < V) {
                float p = pgen * bf2f((unsigned short)ev[k]) * inv;
                op[vv] = p;
                if (p > best || (p == best && vv < besti)) { best = p; besti = vv; }
            }
        }
    }
    __syncthreads();   // dense stores drained (vmcnt(0) before barrier)
    {
        int vv = x[b * NS + t];
        float a = (1.f - pgen) * attn_g[jb * NS + t];
        float old = atomicAdd(&op[vv], a);
        float cand = old + a;   // last add to each vv yields the true final value
        if (cand > best || (cand == best && vv < besti)) { best = cand; besti = vv; }
    }
    bvs[t] = best; bis[t] = besti;
    __syncthreads();
    for (int sft = 128; sft > 0; sft >>= 1) {
        if (t < sft) {
            if (bvs[t + sft] > bvs[t] || (bvs[t + sft] == bvs[t] && bis[t + sft] < bis[t])) {
                bvs[t] = bvs[t + sft]; bis[t] = bis[t + sft];
            }
        }
        __syncthreads();
    }
    int widx = bis[0];
    for (int d = t; d < 512; d += 256) {
        float val = emb[(size_t)widx * 512 + d];
        w_g[jb * 512 + d] = val;
        unsigned short hi = f2bf(val);
        w_hi[jb * 512 + d] = hi;
        w_lo[jb * 512 + d] = f2bf(val - bf2f(hi));
    }
}

extern "C" void kernel_launch(void* const* d_in, const int* in_sizes, int n_in,
                              void* d_out, int out_size, void* d_ws, size_t ws_size,
                              hipStream_t stream) {
    const int*   x     = (const int*)d_in[0];
    const float* enc   = (const float*)d_in[1];
    const float* ench  = (const float*)d_in[2];
    const float* embW  = (const float*)d_in[4];
    const float* slot  = (const float*)d_in[5];
    const float* Wih   = (const float*)d_in[6];
    const float* Whh   = (const float*)d_in[7];
    const float* bih   = (const float*)d_in[8];
    const float* bhh   = (const float*)d_in[9];
    const float* wgenW = (const float*)d_in[10];
    const float* wgenb = (const float*)d_in[11];
    const float* aW    = (const float*)d_in[12];
    const float* ab    = (const float*)d_in[13];
    float* out = (float*)d_out;

    char* ws = (char*)d_ws;
    size_t off = 0;
    auto carve = [&](size_t bytes) { char* p = ws + off; off += (bytes + 255) & ~(size_t)255; return p; };
    unsigned short* emb_bf = (unsigned short*)carve((size_t)V * H * 2);
    unsigned short* wih_hi = (unsigned short*)carve(786432 * 2);
    unsigned short* wih_lo = (unsigned short*)carve(786432 * 2);
    unsigned short* whh_hi = (unsigned short*)carve(786432 * 2);
    unsigned short* whh_lo = (unsigned short*)carve(786432 * 2);
    float* w_f32 = (float*)carve(NR * H * 4);
    float* h_f32 = (float*)carve(NR * H * 4);
    float* ctx0  = (float*)carve(NR * H * 4);
    unsigned short* w_hi = (unsigned short*)carve(NR * H * 2);
    unsigned short* w_lo = (unsigned short*)carve(NR * H * 2);
    unsigned short* h_hi = (unsigned short*)carve(NR * H * 2);
    unsigned short* h_lo = (unsigned short*)carve(NR * H * 2);
    float* gi   = (float*)carve(NR * 1536 * 4);
    float* gh   = (float*)carve(NR * 1536 * 4);
    float* attn = (float*)carve(NR * NS * 4);
    float* pgen = (float*)carve(NR * 4);
    unsigned short* E = (unsigned short*)carve((size_t)NR * EV * 2);

    k_setup_emb<<<7500, 256, 0, stream>>>(embW, emb_bf, (V * H) / 8);
    k_setup_small<<<3392, 256, 0, stream>>>(Wih, Whh, wih_hi, wih_lo, whh_hi, whh_lo,
                                            slot, ench, w_f32, w_hi, w_lo, h_f32, h_hi, h_lo);
    for (int t = 0; t < NT; t++) {
        k_gru_gemm<<<dim3(12, 10, 2), 256, 0, stream>>>(w_hi, w_lo, h_hi, h_lo,
                                                        wih_hi, wih_lo, whh_hi, whh_lo, gi, gh);
        k_attention<<<NR, 256, 0, stream>>>(gi, gh, bih, bhh, h_f32, h_hi, h_lo, enc, x,
                                            w_f32, wgenW, wgenb, attn, pgen, ctx0, t == 0 ? 1 : 0);
        if (t == 0) k_gates<<<NR, 256, 0, stream>>>(ctx0, aW, ab, out);
        k_vgemm<<<240, 256, 0, stream>>>(h_hi, emb_bf, E);
        k_finalize<<<NR, 256, 0, stream>>>(E, pgen, attn, x, embW, out, w_f32, w_hi, w_lo, t);
    }
}

// Round 2
// 1102.324 us; speedup vs baseline: 1.1236x; 1.1236x over previous
//
#include <hip/hip_runtime.h>
#include <math.h>

#define V 30000
#define H 512
#define NB 16
#define NS 256
#define NJ 10
#define NT 8
#define NOPS 4
#define NR 160          // NJ*NB rows
#define EV 30720        // padded E row stride
#define NEGV -1e9f

typedef __attribute__((ext_vector_type(8))) short short8;
typedef __attribute__((ext_vector_type(4))) short short4v;
typedef __attribute__((ext_vector_type(4))) float f32x4;

__device__ inline float bf2f(unsigned short s) {
    union { unsigned int u; float f; } c; c.u = ((unsigned int)s) << 16;
    return c.f;
}
__device__ inline unsigned short f2bf(float f) {
    union { float f; unsigned int u; } c; c.f = f;
    unsigned int u = c.u;
    u += 0x7fffu + ((u >> 16) & 1u);   // RNE
    return (unsigned short)(u >> 16);
}
__device__ inline unsigned long long packkey(float f, int v) {
    union { float f; unsigned int u; } c; c.f = f;
    return ((unsigned long long)c.u << 32) | (unsigned int)(0x7FFFFFFF - v);
}

// ---------------- setup: convert emb_W to bf16 ----------------
__global__ void k_setup_emb(const float* __restrict__ emb, unsigned short* __restrict__ emb_bf, int n8) {
    int gid = blockIdx.x * 256 + threadIdx.x;
    if (gid >= n8) return;
    const float4* src = (const float4*)emb + (size_t)gid * 2;
    float4 a = src[0], b = src[1];
    short8 o;
    o[0] = (short)f2bf(a.x); o[1] = (short)f2bf(a.y); o[2] = (short)f2bf(a.z); o[3] = (short)f2bf(a.w);
    o[4] = (short)f2bf(b.x); o[5] = (short)f2bf(b.y); o[6] = (short)f2bf(b.z); o[7] = (short)f2bf(b.w);
    *(short8*)(emb_bf + (size_t)gid * 8) = o;
}

// ---------------- setup: W splits + initial w/h state ----------------
__global__ void k_setup_small(const float* __restrict__ Wih, const float* __restrict__ Whh,
    unsigned short* wih_hi, unsigned short* wih_lo, unsigned short* whh_hi, unsigned short* whh_lo,
    const float* __restrict__ slot, const float* __restrict__ ench,
    float* w_g, unsigned short* w_hi, unsigned short* w_lo,
    float* h_g, unsigned short* h_hi, unsigned short* h_lo)
{
    int gid = blockIdx.x * 256 + threadIdx.x;
    if (gid < 786432) {
        float v1 = Wih[gid];
        unsigned short hi = f2bf(v1);
        wih_hi[gid] = hi; wih_lo[gid] = f2bf(v1 - bf2f(hi));
        float v2 = Whh[gid];
        hi = f2bf(v2);
        whh_hi[gid] = hi; whh_lo[gid] = f2bf(v2 - bf2f(hi));
    } else {
        int i = gid - 786432;
        if (i < NR * H) {
            int jb = i >> 9, d = i & 511;
            int j = jb >> 4, b = jb & 15;
            float wv = slot[j * H + d];
            w_g[i] = wv;
            unsigned short hi = f2bf(wv);
            w_hi[i] = hi; w_lo[i] = f2bf(wv - bf2f(hi));
            float hv = ench[b * H + d];
            h_g[i] = hv;
            hi = f2bf(hv);
            h_hi[i] = hi; h_lo[i] = f2bf(hv - bf2f(hi));
        }
    }
}

// ---------------- GRU GEMMs: gi = w @ W_ih^T, gh = h @ W_hh^T (split-bf16, fp32-accurate) ----
#define GRU_APAD 520
__global__ __launch_bounds__(256) void k_gru_gemm(
    const unsigned short* __restrict__ w_hi, const unsigned short* __restrict__ w_lo,
    const unsigned short* __restrict__ h_hi, const unsigned short* __restrict__ h_lo,
    const unsigned short* __restrict__ wih_hi, const unsigned short* __restrict__ wih_lo,
    const unsigned short* __restrict__ whh_hi, const unsigned short* __restrict__ whh_lo,
    float* __restrict__ gi, float* __restrict__ gh)
{
    __shared__ unsigned short Ah[16 * GRU_APAD];
    __shared__ unsigned short Al[16 * GRU_APAD];
    int nch = blockIdx.x, mt = blockIdx.y, z = blockIdx.z;
    const unsigned short* Asrc_hi = z ? h_hi : w_hi;
    const unsigned short* Asrc_lo = z ? h_lo : w_lo;
    const unsigned short* Bhi = z ? whh_hi : wih_hi;
    const unsigned short* Blo = z ? whh_lo : wih_lo;
    float* outp = z ? gh : gi;
    int t = threadIdx.x;
    for (int i = t; i < 2048; i += 256) {
        int matl = i >> 10;
        int row = (i >> 6) & 15;
        int seg = i & 63;
        const unsigned short* src = (matl ? Asrc_lo : Asrc_hi) + (mt * 16 + row) * 512 + seg * 8;
        unsigned short* dst = (matl ? Al : Ah) + row * GRU_APAD + seg * 8;
        *(short8*)dst = *(const short8*)src;
    }
    __syncthreads();
    int wv = t >> 6, lane = t & 63;
    int col15 = lane & 15, quad = lane >> 4;
    f32x4 acc0 = {0.f, 0.f, 0.f, 0.f}, acc1 = {0.f, 0.f, 0.f, 0.f};
    int c0 = nch * 128 + wv * 32 + col15;
    int c1 = c0 + 16;
    const unsigned short* bhp0 = Bhi + c0 * 512 + quad * 8;
    const unsigned short* bhp1 = Bhi + c1 * 512 + quad * 8;
    const unsigned short* blp0 = Blo + c0 * 512 + quad * 8;
    const unsigned short* blp1 = Blo + c1 * 512 + quad * 8;
    const unsigned short* ahp = Ah + col15 * GRU_APAD + quad * 8;
    const unsigned short* alp = Al + col15 * GRU_APAD + quad * 8;
#pragma unroll
    for (int ks = 0; ks < 16; ks++) {
        int ko = ks * 32;
        short8 bh0 = *(const short8*)(bhp0 + ko);
        short8 bh1 = *(const short8*)(bhp1 + ko);
        short8 bl0 = *(const short8*)(blp0 + ko);
        short8 bl1 = *(const short8*)(blp1 + ko);
        short8 ah = *(const short8*)(ahp + ko);
        short8 al = *(const short8*)(alp + ko);
        acc0 = __builtin_amdgcn_mfma_f32_16x16x32_bf16(ah, bh0, acc0, 0, 0, 0);
        acc1 = __builtin_amdgcn_mfma_f32_16x16x32_bf16(ah, bh1, acc1, 0, 0, 0);
        acc0 = __builtin_amdgcn_mfma_f32_16x16x32_bf16(ah, bl0, acc0, 0, 0, 0);
        acc1 = __builtin_amdgcn_mfma_f32_16x16x32_bf16(ah, bl1, acc1, 0, 0, 0);
        acc0 = __builtin_amdgcn_mfma_f32_16x16x32_bf16(al, bh0, acc0, 0, 0, 0);
        acc1 = __builtin_amdgcn_mfma_f32_16x16x32_bf16(al, bh1, acc1, 0, 0, 0);
    }
#pragma unroll
    for (int r = 0; r < 4; r++) {
        int row = mt * 16 + quad * 4 + r;
        outp[row * 1536 + c0] = acc0[r];
        outp[row * 1536 + c1] = acc1[r];
    }
}

// --------- fused: GRU pointwise + attention scores + softmax + context + p_gen -------------
__global__ __launch_bounds__(256) void k_attention(
    const float* __restrict__ gi, const float* __restrict__ gh,
    const float* __restrict__ b_ih, const float* __restrict__ b_hh,
    float* __restrict__ h_g, unsigned short* __restrict__ h_hi, unsigned short* __restrict__ h_lo,
    const float* __restrict__ enc, const int* __restrict__ x,
    const float* __restrict__ w_g, const float* __restrict__ wgenW, const float* __restrict__ wgenb,
    float* __restrict__ attn_g, float* __restrict__ pgen_g,
    float* __restrict__ ctx0, int store_ctx,
    float* __restrict__ rowsum, unsigned long long* __restrict__ argpk)
{
    __shared__ float h_lds[512];
    __shared__ float sc[256];
    __shared__ float red[256];
    __shared__ float ctxp[4 * 512];
    int jb = blockIdx.x;
    int b = jb & 15;
    int t = threadIdx.x;
    if (t == 0) { rowsum[jb] = 0.f; argpk[jb] = 0ull; }   // zeroed for this step's vgemm
    // GRU pointwise (PyTorch gate order r,z,n)
    for (int d = t; d < 512; d += 256) {
        int base = jb * 1536;
        float ir = gi[base + d]        + b_ih[d];
        float iz = gi[base + 512 + d]  + b_ih[512 + d];
        float in = gi[base + 1024 + d] + b_ih[1024 + d];
        float hr = gh[base + d]        + b_hh[d];
        float hz = gh[base + 512 + d]  + b_hh[512 + d];
        float hn = gh[base + 1024 + d] + b_hh[1024 + d];
        float hold = h_g[jb * 512 + d];
        float r = 1.f / (1.f + expf(-(ir + hr)));
        float z = 1.f / (1.f + expf(-(iz + hz)));
        float n = tanhf(in + r * hn);
        float hnew = (1.f - z) * n + z * hold;
        h_lds[d] = hnew;
        h_g[jb * 512 + d] = hnew;
        unsigned short hi = f2bf(hnew);
        h_hi[jb * 512 + d] = hi;
        h_lo[jb * 512 + d] = f2bf(hnew - bf2f(hi));
    }
    __syncthreads();
    int wid = t >> 6, lane = t & 63;
    float hreg[8];
#pragma unroll
    for (int i = 0; i < 8; i++) hreg[i] = h_lds[lane * 8 + i];
    const float* encb = enc + (size_t)b * NS * H;
    for (int s = wid; s < NS; s += 4) {
        const float4* er = (const float4*)(encb + s * 512 + lane * 8);
        float4 e0 = er[0], e1 = er[1];
        float p = e0.x * hreg[0] + e0.y * hreg[1] + e0.z * hreg[2] + e0.w * hreg[3]
                + e1.x * hreg[4] + e1.y * hreg[5] + e1.z * hreg[6] + e1.w * hreg[7];
#pragma unroll
        for (int off = 32; off > 0; off >>= 1) p += __shfl_down(p, off);
        if (lane == 0) sc[s] = (x[b * NS + s] == 0) ? NEGV : p;
    }
    __syncthreads();
    // softmax over s
    red[t] = sc[t];
    __syncthreads();
    for (int sft = 128; sft > 0; sft >>= 1) { if (t < sft) red[t] = fmaxf(red[t], red[t + sft]); __syncthreads(); }
    float m = red[0];
    __syncthreads();
    float e = expf(sc[t] - m);
    red[t] = e;
    __syncthreads();
    for (int sft = 128; sft > 0; sft >>= 1) { if (t < sft) red[t] += red[t + sft]; __syncthreads(); }
    float inv = 1.f / red[0];
    float p_s = e * inv;
    sc[t] = p_s;
    attn_g[jb * NS + t] = p_s;
    __syncthreads();
    // context: wave `wid` covers s in [wid*64, wid*64+64), lane covers 8 dims
    {
        float cp[8] = {0.f,0.f,0.f,0.f,0.f,0.f,0.f,0.f};
        const float* encw = encb + lane * 8;
        for (int s = wid * 64; s < wid * 64 + 64; s++) {
            float ps = sc[s];
            const float4* er = (const float4*)(encw + s * 512);
            float4 e0 = er[0], e1 = er[1];
            cp[0] += ps * e0.x; cp[1] += ps * e0.y; cp[2] += ps * e0.z; cp[3] += ps * e0.w;
            cp[4] += ps * e1.x; cp[5] += ps * e1.y; cp[6] += ps * e1.z; cp[7] += ps * e1.w;
        }
        float* cw = ctxp + wid * 512 + lane * 8;
#pragma unroll
        for (int i = 0; i < 8; i++) cw[i] = cp[i];
    }
    __syncthreads();
    int d0 = 2 * t, d1 = 2 * t + 1;
    float c0 = ctxp[d0] + ctxp[512 + d0] + ctxp[1024 + d0] + ctxp[1536 + d0];
    float c1 = ctxp[d1] + ctxp[512 + d1] + ctxp[1024 + d1] + ctxp[1536 + d1];
    if (store_ctx) ((float2*)ctx0)[jb * 256 + t] = make_float2(c0, c1);
    float pg = wgenW[d0] * w_g[jb * 512 + d0] + wgenW[d1] * w_g[jb * 512 + d1]
             + wgenW[512 + d0] * h_lds[d0] + wgenW[512 + d1] * h_lds[d1]
             + wgenW[1024 + d0] * c0 + wgenW[1024 + d1] * c1;
    __syncthreads();
    red[t] = pg;
    __syncthreads();
    for (int sft = 128; sft > 0; sft >>= 1) { if (t < sft) red[t] += red[t + sft]; __syncthreads(); }
    if (t == 0) pgen_g[jb] = 1.f / (1.f + expf(-(red[0] + wgenb[0])));
}

// ------- vocab GEMM: E = exp(h @ embW^T) bf16 (coalesced), + rowsum + dense argmax -------
#define VPAD 136
__global__ __launch_bounds__(256) void k_vgemm(
    const unsigned short* __restrict__ h_hi, const unsigned short* __restrict__ emb_bf,
    unsigned short* __restrict__ E, float* __restrict__ rowsum,
    unsigned long long* __restrict__ argpk)
{
    __shared__ unsigned short A[160 * VPAD];   // staging, then reused as transpose buffer
    int blk = blockIdx.x;
    int t = threadIdx.x;
    int wv = t >> 6, lane = t & 63, col15 = lane & 15, quad = lane >> 4;
    int v = blk * 128 + wv * 32 + col15;
    f32x4 acc[10][2];
#pragma unroll
    for (int m = 0; m < 10; m++) {
        acc[m][0] = (f32x4){0.f, 0.f, 0.f, 0.f};
        acc[m][1] = (f32x4){0.f, 0.f, 0.f, 0.f};
    }
    int v0c = min(v, V - 1);
    int v1c = min(v + 16, V - 1);
    for (int kc = 0; kc < 4; kc++) {
        __syncthreads();
        for (int i = t; i < 2560; i += 256) {
            int row = i >> 4, seg = i & 15;
            *(short8*)(A + row * VPAD + seg * 8) = *(const short8*)(h_hi + row * 512 + kc * 128 + seg * 8);
        }
        __syncthreads();
#pragma unroll
        for (int ks = 0; ks < 4; ks++) {
            int kl = ks * 32 + quad * 8;
            int kg = kc * 128 + kl;
            short8 b0 = *(const short8*)(emb_bf + (size_t)v0c * 512 + kg);
            short8 b1 = *(const short8*)(emb_bf + (size_t)v1c * 512 + kg);
#pragma unroll
            for (int m = 0; m < 10; m++) {
                short8 a = *(const short8*)(A + (m * 16 + col15) * VPAD + kl);
                acc[m][0] = __builtin_amdgcn_mfma_f32_16x16x32_bf16(a, b0, acc[m][0], 0, 0, 0);
                acc[m][1] = __builtin_amdgcn_mfma_f32_16x16x32_bf16(a, b1, acc[m][1], 0, 0, 0);
            }
        }
    }
    __syncthreads();   // all LDS A reads done; reuse as transpose buffer
    // exp + transpose into LDS: A[row * VPAD + col_local] (bf16)
#pragma unroll
    for (int m = 0; m < 10; m++) {
#pragma unroll
        for (int tile = 0; tile < 2; tile++) {
            int vv = v + tile * 16;
            int cl = wv * 32 + tile * 16 + col15;
#pragma unroll
            for (int r = 0; r < 4; r++) {
                int row = m * 16 + quad * 4 + r;
                float ev = (vv < V) ? expf(acc[m][tile][r]) : 0.f;
                A[row * VPAD + cl] = f2bf(ev);
            }
        }
    }
    __syncthreads();
    // per-row sum + max over this block's 128 cols
    if (t < 160) {
        float s = 0.f;
        unsigned long long key = 0ull;
#pragma unroll
        for (int seg = 0; seg < 16; seg++) {
            short8 ev = *(const short8*)(A + t * VPAD + seg * 8);
#pragma unroll
            for (int k = 0; k < 8; k++) {
                float f = bf2f((unsigned short)ev[k]);
                s += f;
                unsigned long long kk = packkey(f, blk * 128 + seg * 8 + k);
                key = (kk > key) ? kk : key;
            }
        }
        atomicAdd(rowsum + t, s);
        atomicMax(argpk + t, key);
    }
    // coalesced E store: 16 lanes per row (short8 each), 16 rows in flight, 10 iters
    {
        int rsub = t >> 4, seg = t & 15;
        for (int it = 0; it < 10; it++) {
            int row = it * 16 + rsub;
            short8 ev = *(const short8*)(A + row * VPAD + seg * 8);
            *(short8*)(E + (size_t)row * EV + blk * 128 + seg * 8) = ev;
        }
    }
}

// ------- finalize: scale+write dense (coalesced), scatter, argmax, w_next, gates@t0 -------
__global__ __launch_bounds__(256) void k_finalize(
    const unsigned short* __restrict__ E, const float* __restrict__ pgen_g,
    const float* __restrict__ rowsum, const unsigned long long* __restrict__ argpk,
    const float* __restrict__ attn_g, const int* __restrict__ x,
    const float* __restrict__ emb, float* __restrict__ out,
    float* __restrict__ w_g, unsigned short* __restrict__ w_hi, unsigned short* __restrict__ w_lo,
    const float* __restrict__ ctx0, const float* __restrict__ aW, const float* __restrict__ ab,
    int tstep)
{
    __shared__ float bvs[256];
    __shared__ int bis[256];
    __shared__ float red[256];
    int jb = blockIdx.x, t = threadIdx.x;
    int j = jb >> 4, b = jb & 15;
    float inv = 1.f / rowsum[jb];
    float pgen = pgen_g[jb];
    float scale = pgen * inv;
    const unsigned short* Er = E + (size_t)jb * EV;
    size_t outbase = (size_t)640 + ((size_t)(b * NJ + j) * NT + tstep) * V;
    float* op = out + outbase;
    // dense write: lane-consecutive float4 stores
    for (int c = 0; c < 29; c++) {
        int vv = c * 1024 + t * 4;
        short4v e = *(const short4v*)(Er + vv);
        float4 p = make_float4(bf2f((unsigned short)e[0]) * scale, bf2f((unsigned short)e[1]) * scale,
                               bf2f((unsigned short)e[2]) * scale, bf2f((unsigned short)e[3]) * scale);
        *(float4*)(op + vv) = p;
    }
    if (t < 76) {
        int vv = 29696 + t * 4;
        short4v e = *(const short4v*)(Er + vv);
        float4 p = make_float4(bf2f((unsigned short)e[0]) * scale, bf2f((unsigned short)e[1]) * scale,
                               bf2f((unsigned short)e[2]) * scale, bf2f((unsigned short)e[3]) * scale);
        *(float4*)(op + vv) = p;
    }
    __syncthreads();   // dense stores drained before scatter atomics
    // pointer scatter + candidate tracking
    float best; int besti;
    {
        int vv = x[b * NS + t];
        float a = (1.f - pgen) * attn_g[jb * NS + t];
        float old = atomicAdd(&op[vv], a);
        best = old + a;    // last adder to each vv sees the true final value
        besti = vv;
    }
    bvs[t] = best; bis[t] = besti;
    __syncthreads();
    for (int sft = 128; sft > 0; sft >>= 1) {
        if (t < sft) {
            if (bvs[t + sft] > bvs[t] || (bvs[t + sft] == bvs[t] && bis[t + sft] < bis[t])) {
                bvs[t] = bvs[t + sft]; bis[t] = bis[t + sft];
            }
        }
        __syncthreads();
    }
    // combine with dense argmax from vgemm
    int widx;
    {
        unsigned long long key = argpk[jb];
        union { unsigned int u; float f; } c; c.u = (unsigned int)(key >> 32);
        float db = c.f * scale;
        int di = 0x7FFFFFFF - (int)(key & 0xFFFFFFFFu);
        float sb = bvs[0]; int si = bis[0];
        widx = (sb > db || (sb == db && si < di)) ? si : di;
    }
    // w_next gather + bf16 split
    for (int d = t; d < 512; d += 256) {
        float val = emb[(size_t)widx * 512 + d];
        w_g[jb * 512 + d] = val;
        unsigned short hi = f2bf(val);
        w_hi[jb * 512 + d] = hi;
        w_lo[jb * 512 + d] = f2bf(val - bf2f(hi));
    }
    // gate head (uses step-0 context)
    if (tstep == 0) {
        float part[4] = {0.f, 0.f, 0.f, 0.f};
        for (int d = t; d < 512; d += 256) {
            float c = ctx0[jb * 512 + d];
#pragma unroll
            for (int o = 0; o < 4; o++) part[o] += c * aW[o * 512 + d];
        }
        for (int o = 0; o < 4; o++) {
            __syncthreads();
            red[t] = part[o];
            __syncthreads();
            for (int sft = 128; sft > 0; sft >>= 1) { if (t < sft) red[t] += red[t + sft]; __syncthreads(); }
            if (t == 0) out[(b * NJ + j) * NOPS + o] = red[0] + ab[o];
        }
    }
}

extern "C" void kernel_launch(void* const* d_in, const int* in_sizes, int n_in,
                              void* d_out, int out_size, void* d_ws, size_t ws_size,
                              hipStream_t stream) {
    const int*   x     = (const int*)d_in[0];
    const float* enc   = (const float*)d_in[1];
    const float* ench  = (const float*)d_in[2];
    const float* embW  = (const float*)d_in[4];
    const float* slot  = (const float*)d_in[5];
    const float* Wih   = (const float*)d_in[6];
    const float* Whh   = (const float*)d_in[7];
    const float* bih   = (const float*)d_in[8];
    const float* bhh   = (const float*)d_in[9];
    const float* wgenW = (const float*)d_in[10];
    const float* wgenb = (const float*)d_in[11];
    const float* aW    = (const float*)d_in[12];
    const float* ab    = (const float*)d_in[13];
    float* out = (float*)d_out;

    char* ws = (char*)d_ws;
    size_t off = 0;
    auto carve = [&](size_t bytes) { char* p = ws + off; off += (bytes + 255) & ~(size_t)255; return p; };
    unsigned short* emb_bf = (unsigned short*)carve((size_t)V * H * 2);
    unsigned short* wih_hi = (unsigned short*)carve(786432 * 2);
    unsigned short* wih_lo = (unsigned short*)carve(786432 * 2);
    unsigned short* whh_hi = (unsigned short*)carve(786432 * 2);
    unsigned short* whh_lo = (unsigned short*)carve(786432 * 2);
    float* w_f32 = (float*)carve(NR * H * 4);
    float* h_f32 = (float*)carve(NR * H * 4);
    float* ctx0  = (float*)carve(NR * H * 4);
    unsigned short* w_hi = (unsigned short*)carve(NR * H * 2);
    unsigned short* w_lo = (unsigned short*)carve(NR * H * 2);
    unsigned short* h_hi = (unsigned short*)carve(NR * H * 2);
    unsigned short* h_lo = (unsigned short*)carve(NR * H * 2);
    float* gi   = (float*)carve(NR * 1536 * 4);
    float* gh   = (float*)carve(NR * 1536 * 4);
    float* attn = (float*)carve(NR * NS * 4);
    float* pgen = (float*)carve(NR * 4);
    float* rowsum = (float*)carve(NR * 4);
    unsigned long long* argpk = (unsigned long long*)carve(NR * 8);
    unsigned short* E = (unsigned short*)carve((size_t)NR * EV * 2);

    k_setup_emb<<<7500, 256, 0, stream>>>(embW, emb_bf, (V * H) / 8);
    k_setup_small<<<3392, 256, 0, stream>>>(Wih, Whh, wih_hi, wih_lo, whh_hi, whh_lo,
                                            slot, ench, w_f32, w_hi, w_lo, h_f32, h_hi, h_lo);
    for (int t = 0; t < NT; t++) {
        k_gru_gemm<<<dim3(12, 10, 2), 256, 0, stream>>>(w_hi, w_lo, h_hi, h_lo,
                                                        wih_hi, wih_lo, whh_hi, whh_lo, gi, gh);
        k_attention<<<NR, 256, 0, stream>>>(gi, gh, bih, bhh, h_f32, h_hi, h_lo, enc, x,
                                            w_f32, wgenW, wgenb, attn, pgen, ctx0, t == 0 ? 1 : 0,
                                            rowsum, argpk);
        k_vgemm<<<240, 256, 0, stream>>>(h_hi, emb_bf, E, rowsum, argpk);
        k_finalize<<<NR, 256, 0, stream>>>(E, pgen, rowsum, argpk, attn, x, embW, out,
                                           w_f32, w_hi, w_lo, ctx0, aW, ab, t);
    }
}